// Round 1
// baseline (18.036 us; speedup 1.0000x reference)
//
#include <hip/hip_runtime.h>

#define NATOMS 25000
#define NSP 64
#define NRANGE 16
#define RSIZE ((NATOMS + NRANGE - 1) / NRANGE)   // 1563 atoms per range

typedef short bf16x8 __attribute__((ext_vector_type(8)));   // 8 bf16 = 4 VGPRs
typedef float f32x4  __attribute__((ext_vector_type(4)));
typedef unsigned short u16;

// f32 -> bf16 round-to-nearest-even (inputs are finite, no NaN handling needed)
__device__ __forceinline__ u16 f2bf(float f) {
  unsigned u = __float_as_uint(f);
  u += 0x7fffu + ((u >> 16) & 1u);
  return (u16)(u >> 16);
}

__global__ __launch_bounds__(256)
void zcl_kernel(const float* __restrict__ feat,
                const int*   __restrict__ sp,
                const float* __restrict__ weight,
                const float* __restrict__ bias,
                float*       __restrict__ out)
{
  // W[o][i] as bf16, rows of 128; 16B chunks XOR-swizzled by (row&7) so
  // MFMA B-frag ds_read_b128 spreads evenly over all 32 banks.
  __shared__ u16 Ws[128 * 128];              // 32 KiB
  __shared__ u16 As[16 * 128];               // 4 KiB, same swizzle
  __shared__ u16 list[((RSIZE + 15) & ~15) + 16];  // worst-case all atoms match
  __shared__ int nM;

  const int tid = threadIdx.x;
  const int bid = blockIdx.x;
  const int s  = bid >> 4;                   // species: 16 consecutive blocks share W[s]
  const int r  = bid & (NRANGE - 1);         // atom range
  const int lo = r * RSIZE;
  const int hi = (lo + RSIZE < NATOMS) ? (lo + RSIZE) : NATOMS;

  if (tid == 0) nM = 0;

  const int wv   = tid >> 6;                 // wave 0..3 owns outputs [32w,32w+32)
  const int lane = tid & 63;
  const int l16  = lane & 15;
  const int kq   = lane >> 4;                // 0..3
  const int o0   = wv * 32 + l16;
  const float bv0 = bias[s * 128 + o0];      // hoisted bias (L2-hot, 32 KB total)
  const float bv1 = bias[s * 128 + o0 + 16];

  // ---- stage W[s] -> LDS bf16, swizzled. 2048 16B-chunks, 8 iters x 256 thr ----
  const float4* wg = (const float4*)(weight + (size_t)s * (128 * 128));
  #pragma unroll
  for (int j = 0; j < 8; ++j) {
    int chunk = j * 256 + tid;               // 0..2047
    int row = chunk >> 4;                    // output row o
    int c   = chunk & 15;                    // 8-elem group along i
    float4 v0 = wg[row * 32 + c * 2];
    float4 v1 = wg[row * 32 + c * 2 + 1];
    union { u16 h[8]; bf16x8 v; } uu;
    uu.h[0] = f2bf(v0.x); uu.h[1] = f2bf(v0.y);
    uu.h[2] = f2bf(v0.z); uu.h[3] = f2bf(v0.w);
    uu.h[4] = f2bf(v1.x); uu.h[5] = f2bf(v1.y);
    uu.h[6] = f2bf(v1.z); uu.h[7] = f2bf(v1.w);
    *(bf16x8*)&Ws[row * 128 + ((c ^ (row & 7)) << 3)] = uu.v;
  }

  __syncthreads();   // nM init + Ws writes visible

  // ---- compact atoms of species s in [lo,hi) into LDS list (order-free) ----
  for (int a0 = lo; a0 < hi; a0 += 256) {
    int a = a0 + tid;
    bool m = (a < hi) && (sp[a] == s);
    unsigned long long mk = __ballot(m);
    int base = 0;
    if (lane == 0) base = atomicAdd(&nM, __popcll(mk));
    base = __shfl(base, 0);
    if (m) list[base + __popcll(mk & ((1ull << lane) - 1ull))] = (u16)a;
  }
  __syncthreads();

  const int nMatch = nM;
  const int ntile  = (nMatch + 15) >> 4;

  for (int t = 0; t < ntile; ++t) {
    __syncthreads();   // previous tile's As readers done
    // ---- gather 16 atom feature rows -> LDS bf16 (16 rows x 16 threads) ----
    {
      int row = tid >> 4, c = tid & 15;
      int li  = t * 16 + row;
      int atom = list[li < nMatch ? li : 0];   // tail rows load a dummy valid row
      const float4* xg = (const float4*)(feat + (size_t)atom * 128);
      float4 v0 = xg[c * 2];
      float4 v1 = xg[c * 2 + 1];
      union { u16 h[8]; bf16x8 v; } uu;
      uu.h[0] = f2bf(v0.x); uu.h[1] = f2bf(v0.y);
      uu.h[2] = f2bf(v0.z); uu.h[3] = f2bf(v0.w);
      uu.h[4] = f2bf(v1.x); uu.h[5] = f2bf(v1.y);
      uu.h[6] = f2bf(v1.z); uu.h[7] = f2bf(v1.w);
      *(bf16x8*)&As[row * 128 + ((c ^ (row & 7)) << 3)] = uu.v;
    }
    __syncthreads();

    // ---- 16(M) x 32(N per wave) x 128(K): 8 MFMAs ----
    f32x4 acc0 = {0.f, 0.f, 0.f, 0.f};
    f32x4 acc1 = {0.f, 0.f, 0.f, 0.f};
    const int br0 = wv * 32 + l16;     // B rows = output indices
    const int br1 = br0 + 16;
    #pragma unroll
    for (int ks = 0; ks < 4; ++ks) {
      int slot = ks * 4 + kq;          // 16B chunk along K
      bf16x8 av = *(const bf16x8*)&As[l16 * 128 + ((slot ^ (l16 & 7)) << 3)];
      bf16x8 b0 = *(const bf16x8*)&Ws[br0 * 128 + ((slot ^ (br0 & 7)) << 3)];
      bf16x8 b1 = *(const bf16x8*)&Ws[br1 * 128 + ((slot ^ (br1 & 7)) << 3)];
      acc0 = __builtin_amdgcn_mfma_f32_16x16x32_bf16(av, b0, acc0, 0, 0, 0);
      acc1 = __builtin_amdgcn_mfma_f32_16x16x32_bf16(av, b1, acc1, 0, 0, 0);
    }

    // ---- store: D row=(lane>>4)*4+q (atom), col=lane&15 (output) ----
    #pragma unroll
    for (int q = 0; q < 4; ++q) {
      int li = t * 16 + kq * 4 + q;
      if (li < nMatch) {
        int atom = list[li];
        float* op = out + (size_t)atom * 128 + o0;
        op[0]  = acc0[q] + bv0;
        op[16] = acc1[q] + bv1;
      }
    }
  }
}

extern "C" void kernel_launch(void* const* d_in, const int* in_sizes, int n_in,
                              void* d_out, int out_size, void* d_ws, size_t ws_size,
                              hipStream_t stream) {
  const float* feat   = (const float*)d_in[0];
  const int*   sp     = (const int*)d_in[1];
  const float* weight = (const float*)d_in[2];
  const float* bias   = (const float*)d_in[3];
  float*       out    = (float*)d_out;
  zcl_kernel<<<NSP * NRANGE, 256, 0, stream>>>(feat, sp, weight, bias, out);
}